// Round 17
// baseline (125.301 us; speedup 1.0000x reference)
//
#include <hip/hip_runtime.h>
#include <hip/hip_bf16.h>

typedef float f32x4 __attribute__((ext_vector_type(4)));
typedef float f32x16 __attribute__((ext_vector_type(16)));
typedef short s16x8 __attribute__((ext_vector_type(8)));

typedef const __attribute__((address_space(1))) unsigned int* as1u;
typedef __attribute__((address_space(3))) unsigned int* as3u;

__device__ __forceinline__ unsigned short f2bf(float f) {
    union { float f; unsigned u; } v; v.f = f;
    unsigned u = v.u;
    u += 0x7fffu + ((u >> 16) & 1u);
    return (unsigned short)(u >> 16);
}

__device__ __forceinline__ void gload16(const void* g, void* l3) {
    __builtin_amdgcn_global_load_lds((as1u)g, (as3u)l3, 16, 0, 0);
}

// XOR-swizzled byte offset for [R][64]-bf16 tiles (128B rows)
__device__ __forceinline__ int swzo(int row, int cb) {
    return row * 128 + (cb ^ ((row & 7) << 4));
}

#define LOG2E 1.4426950408889634f
#define QSCALE (0.125f * LOG2E)   // 1/sqrt(64) * log2(e), folded into Q

// ------------- Kernel P: fused prep -------------
__global__ __launch_bounds__(256) void prep_kernel(
    const float* __restrict__ x, unsigned short* __restrict__ xb,
    const float* __restrict__ W_in, unsigned short* __restrict__ Wt_in,
    const float* __restrict__ W_out, unsigned short* __restrict__ Wot)
{
    const int t = threadIdx.x;
    int blk = blockIdx.x;
    if (blk < 2048) {
        size_t i = ((size_t)blk * 256 + t) * 8;
        float4 a = *(const float4*)&x[i];
        float4 b = *(const float4*)&x[i + 4];
        s16x8 p;
        p[0] = (short)f2bf(a.x); p[1] = (short)f2bf(a.y);
        p[2] = (short)f2bf(a.z); p[3] = (short)f2bf(a.w);
        p[4] = (short)f2bf(b.x); p[5] = (short)f2bf(b.y);
        p[6] = (short)f2bf(b.z); p[7] = (short)f2bf(b.w);
        *(s16x8*)&xb[i] = p;
        return;
    }
    const float* W;
    unsigned short* Wt;
    int N;
    if (blk < 2816) { blk -= 2048; W = W_in;  Wt = Wt_in; N = 3072; }
    else            { blk -= 2816; W = W_out; Wt = Wot;   N = 1024; }
    __shared__ alignas(16) short T[64 * 64];
    const int KB = 16;
    const int kb = blk % KB, nb = blk / KB;
#pragma unroll
    for (int pass = 0; pass < 4; ++pass) {
        int k = pass * 16 + (t >> 4);
        int n4 = (t & 15) * 4;
        float4 v = *(const float4*)&W[(size_t)(kb * 64 + k) * N + nb * 64 + n4];
        short4 s4;
        s4.x = (short)f2bf(v.x); s4.y = (short)f2bf(v.y);
        s4.z = (short)f2bf(v.z); s4.w = (short)f2bf(v.w);
        *(short4*)((char*)T + k * 128 + ((n4 * 2) ^ ((k & 7) << 4))) = s4;
    }
    __syncthreads();
#pragma unroll
    for (int pass = 0; pass < 4; ++pass) {
        int n = pass * 16 + (t >> 4);
        int k4 = (t & 15) * 4;
        short4 s4;
        s4.x = *(const short*)((const char*)T + (k4 + 0) * 128 + ((n * 2) ^ (((k4 + 0) & 7) << 4)));
        s4.y = *(const short*)((const char*)T + (k4 + 1) * 128 + ((n * 2) ^ (((k4 + 1) & 7) << 4)));
        s4.z = *(const short*)((const char*)T + (k4 + 2) * 128 + ((n * 2) ^ (((k4 + 2) & 7) << 4)));
        s4.w = *(const short*)((const char*)T + (k4 + 3) * 128 + ((n * 2) ^ (((k4 + 3) & 7) << 4)));
        *(short4*)&Wt[(size_t)(nb * 64 + n) * 1024 + kb * 64 + k4] = s4;
    }
}

// ---------------- Kernel 1: qkv = x @ W_in + b_in, fused RoPE ----------------
// 256x256 tile, BK=64, 8 waves, LDS 128KB dbuf, counted vmcnt(8) pipeline.
__global__ __launch_bounds__(512, 2) void qkv_rope_kernel(
    const unsigned short* __restrict__ xb, const unsigned short* __restrict__ Wt,
    const float* __restrict__ bias, const float* __restrict__ cosb,
    const float* __restrict__ sinb,
    unsigned short* __restrict__ Qb, unsigned short* __restrict__ Kb,
    unsigned short* __restrict__ Vb)
{
    __shared__ alignas(16) short As[2][256 * 64];
    __shared__ alignas(16) short Bs[2][256 * 64];
    const int bid = blockIdx.x;
    const int mb = bid & 15, nb = bid >> 4;
    const int t = threadIdx.x, w = t >> 6, l = t & 63;
    const int g = l >> 4, j = l & 15;
    const int wm = w >> 2, wn = w & 3;
    const int m0 = mb * 256, n0 = nb * 256;

    f32x4 acc[8][4];
#pragma unroll
    for (int mi = 0; mi < 8; ++mi)
#pragma unroll
        for (int ni = 0; ni < 4; ++ni) acc[mi][ni] = (f32x4){0.f, 0.f, 0.f, 0.f};

#pragma unroll
    for (int i = 0; i < 4; ++i) {
        int p = (w * 4 + i) * 1024 + l * 16;
        int r = p >> 7, lb = (p & 127) ^ ((r & 7) << 4);
        gload16(&xb[(size_t)(m0 + r) * 1024 + (lb >> 1)], (char*)As[0] + (w * 4 + i) * 1024);
        gload16(&Wt[(size_t)(n0 + r) * 1024 + (lb >> 1)], (char*)Bs[0] + (w * 4 + i) * 1024);
    }
    asm volatile("s_waitcnt vmcnt(0)" ::: "memory");
    __builtin_amdgcn_s_barrier();

    for (int kti = 0; kti < 16; ++kti) {
        const int cur = kti & 1, nxt = cur ^ 1;
        const int ktn = ((kti + 1) & 15) * 64;

#pragma unroll
        for (int i = 0; i < 4; ++i) {
            int p = (w * 4 + i) * 1024 + l * 16;
            int r = p >> 7, lb = (p & 127) ^ ((r & 7) << 4);
            gload16(&xb[(size_t)(m0 + r) * 1024 + ktn + (lb >> 1)], (char*)As[nxt] + (w * 4 + i) * 1024);
            gload16(&Wt[(size_t)(n0 + r) * 1024 + ktn + (lb >> 1)], (char*)Bs[nxt] + (w * 4 + i) * 1024);
        }
        asm volatile("s_waitcnt vmcnt(8)" ::: "memory");
        __builtin_amdgcn_s_barrier();

#pragma unroll
        for (int kf = 0; kf < 2; ++kf) {
            s16x8 bv[4];
#pragma unroll
            for (int ni = 0; ni < 4; ++ni)
                bv[ni] = *(const s16x8*)((const char*)Bs[cur] + swzo(wn * 64 + ni * 16 + j, kf * 64 + g * 16));
#pragma unroll
            for (int mh = 0; mh < 2; ++mh) {
                s16x8 af[4];
#pragma unroll
                for (int mi = 0; mi < 4; ++mi)
                    af[mi] = *(const s16x8*)((const char*)As[cur] + swzo(wm * 128 + mh * 64 + mi * 16 + j, kf * 64 + g * 16));
                __builtin_amdgcn_s_setprio(1);
#pragma unroll
                for (int mi = 0; mi < 4; ++mi)
#pragma unroll
                    for (int ni = 0; ni < 4; ++ni)
                        acc[mh * 4 + mi][ni] = __builtin_amdgcn_mfma_f32_16x16x32_bf16(af[mi], bv[ni], acc[mh * 4 + mi][ni], 0, 0, 0);
                __builtin_amdgcn_s_setprio(0);
            }
        }
        __builtin_amdgcn_s_barrier();
    }

    const int row0 = m0 + wm * 128;
    const int col0 = n0 + wn * 64;
    const int sec = col0 >> 10;
    const int h = (col0 & 1023) >> 6;

    if (sec < 2) {
        unsigned short* dst = (sec == 0) ? Qb : Kb;
        const float qs = (sec == 0) ? QSCALE : 1.0f;
#pragma unroll
        for (int nt = 0; nt < 2; ++nt) {
            const int d = nt * 16 + j;
            const float b1 = bias[col0 + d];
            const float b2 = bias[col0 + d + 32];
#pragma unroll
            for (int mi = 0; mi < 8; ++mi) {
#pragma unroll
                for (int r = 0; r < 4; ++r) {
                    int row = row0 + mi * 16 + g * 4 + r;
                    int s = row & 2047, bb = row >> 11;
                    float c = cosb[s * 64 + d], sn = sinb[s * 64 + d];
                    float x1 = acc[mi][nt][r] + b1;
                    float x2 = acc[mi][nt + 2][r] + b2;
                    float lo = (x1 * c - x2 * sn) * qs;
                    float hi = (x1 * sn + x2 * c) * qs;
                    size_t base = ((size_t)(bb * 16 + h) * 2048 + s) * 64;
                    dst[base + d] = f2bf(lo);
                    dst[base + d + 32] = f2bf(hi);
                }
            }
        }
    } else {
#pragma unroll
        for (int nt = 0; nt < 4; ++nt) {
            const int d = nt * 16 + j;
            const float bvv = bias[col0 + d];
#pragma unroll
            for (int mi = 0; mi < 8; ++mi) {
#pragma unroll
                for (int r = 0; r < 4; ++r) {
                    int row = row0 + mi * 16 + g * 4 + r;
                    int s = row & 2047, bb = row >> 11;
                    size_t base = ((size_t)(bb * 16 + h) * 2048 + s) * 64;
                    Vb[base + d] = f2bf(acc[mi][nt][r] + bvv);
                }
            }
        }
    }
}

// ---------------- Kernel 2: flash attention, 32x32x16 MFMA, 4-wave blocks ----------------
// 4 waves x 32 q-rows = 128 q/block, grid 512 (XCD head-swizzle), KVBLK=64,
// LDS 32KB -> 4 blocks/CU = 16 waves/CU. Total LDS traffic halved vs 16x16.
// Swapped QK, fixed max m=0, pack+2xpermlane32 redistribution (R16-verified).
#define NT64 32
__global__ __launch_bounds__(256, 4) void attn_kernel(
    const unsigned short* __restrict__ Qb, const unsigned short* __restrict__ Kb,
    const unsigned short* __restrict__ Vb, unsigned short* __restrict__ AO)
{
    __shared__ alignas(16) short Ks[2][64 * 64];   // [dbuf][key][d] swizzled
    __shared__ alignas(16) short Vt[2][64 * 64];   // [dbuf][d][key] swizzled
    const int bid = blockIdx.x;
    const int bh = (bid & 7) + ((bid >> 7) << 3);  // XCD swizzle (R8-proven)
    const int qt = (bid >> 3) & 15;
    const int t = threadIdx.x, w = t >> 6, l = t & 63;
    const int lq = l & 31, lh = l >> 5;
    const unsigned short* Qh = Qb + (size_t)bh * 131072;
    const unsigned short* Kh = Kb + (size_t)bh * 131072;
    const unsigned short* Vh = Vb + (size_t)bh * 131072;
    const int q0 = qt * 128 + w * 32;

    // Q fragments (B-operand): aq[ds] = Q[q0+lq][ds*16 + lh*8 .. +8]
    s16x8 aq[4];
#pragma unroll
    for (int ds = 0; ds < 4; ++ds)
        aq[ds] = *(const s16x8*)&Qh[(size_t)(q0 + lq) * 64 + ds * 16 + lh * 8];

    float lt_ = 0.f;
    f32x16 o[2];
#pragma unroll
    for (int i = 0; i < 16; ++i) { o[0][i] = 0.f; o[1][i] = 0.f; }

    // staging: all 256 threads; V keys (vk,vk+1) x d [vd,vd+8); K 2 gload16/thread
    const int vk = (t & 31) * 2;
    const int vd = (t >> 5) * 8;

    s16x8 va, vb2;

    // ---- prologue: stage tile 0 ----
    va  = *(const s16x8*)&Vh[(size_t)vk * 64 + vd];
    vb2 = *(const s16x8*)&Vh[(size_t)(vk + 1) * 64 + vd];
#pragma unroll
    for (int i = 0; i < 2; ++i) {
        int p = (w * 2 + i) * 1024 + l * 16;
        int r = p >> 7, lb = (p & 127) ^ ((r & 7) << 4);
        gload16(&Kh[(size_t)r * 64 + (lb >> 1)], (char*)Ks[0] + (w * 2 + i) * 1024);
    }
    asm volatile("s_waitcnt vmcnt(0)" ::: "memory");
#pragma unroll
    for (int dd = 0; dd < 8; ++dd) {
        int d = vd + dd;
        unsigned pkv = (unsigned)(unsigned short)va[dd] | ((unsigned)(unsigned short)vb2[dd] << 16);
        *(unsigned*)((char*)Vt[0] + d * 128 + ((vk * 2) ^ ((d & 7) << 4))) = pkv;
    }
    asm volatile("s_waitcnt lgkmcnt(0)" ::: "memory");
    __builtin_amdgcn_s_barrier();

    for (int tt = 0; tt < NT64; ++tt) {
        const int cur = tt & 1, nxt = cur ^ 1;
        const int kvp = ((tt + 1) & (NT64 - 1)) * 64;

        // ---- prefetch tile tt+1 ----
        va  = *(const s16x8*)&Vh[(size_t)(kvp + vk) * 64 + vd];
        vb2 = *(const s16x8*)&Vh[(size_t)(kvp + vk + 1) * 64 + vd];
#pragma unroll
        for (int i = 0; i < 2; ++i) {
            int p = (w * 2 + i) * 1024 + l * 16;
            int r = p >> 7, lb = (p & 127) ^ ((r & 7) << 4);
            gload16(&Kh[(size_t)(kvp + r) * 64 + (lb >> 1)], (char*)Ks[nxt] + (w * 2 + i) * 1024);
        }

        // ---- QK^T: sc[kh] = S[key=kh*32+rowmap][q=q0+lq] ----
        const char* kbase = (const char*)Ks[cur];
        const char* vbase = (const char*)Vt[cur];
        f32x16 sc[2];
#pragma unroll
        for (int i = 0; i < 16; ++i) { sc[0][i] = 0.f; sc[1][i] = 0.f; }
        __builtin_amdgcn_s_setprio(1);
#pragma unroll
        for (int kh = 0; kh < 2; ++kh)
#pragma unroll
            for (int ds = 0; ds < 4; ++ds) {
                s16x8 kf = *(const s16x8*)(kbase + swzo(kh * 32 + lq, ds * 32 + lh * 16));
                sc[kh] = __builtin_amdgcn_mfma_f32_32x32x16_bf16(kf, aq[ds], sc[kh], 0, 0, 0);
            }
        __builtin_amdgcn_s_setprio(0);

        // ---- softmax fixed max=0 (log2 domain) ----
        float rs = 0.f;
#pragma unroll
        for (int kh = 0; kh < 2; ++kh)
#pragma unroll
            for (int r = 0; r < 16; ++r) {
                sc[kh][r] = __builtin_amdgcn_exp2f(sc[kh][r]);
                rs += sc[kh][r];
            }
        lt_ += rs;

        // ---- per key-half: pack, redistribute, PV ----
#pragma unroll
        for (int kh = 0; kh < 2; ++kh) {
            unsigned X[8];
#pragma unroll
            for (int i = 0; i < 8; ++i)
                asm("v_cvt_pk_bf16_f32 %0, %1, %2"
                    : "=v"(X[i]) : "v"(sc[kh][2 * i]), "v"(sc[kh][2 * i + 1]));
#pragma unroll
            for (int ks = 0; ks < 2; ++ks) {
                unsigned a0 = X[ks * 4 + 0], a1 = X[ks * 4 + 1];
                unsigned b0 = X[ks * 4 + 2], b1 = X[ks * 4 + 3];
                asm("v_permlane32_swap_b32 %0, %1" : "+v"(a0), "+v"(b0));
                asm("v_permlane32_swap_b32 %0, %1" : "+v"(a1), "+v"(b1));
                union { unsigned u[4]; s16x8 v; } fr;
                fr.u[0] = a0; fr.u[1] = a1; fr.u[2] = b0; fr.u[3] = b1;
                const int kst = kh * 2 + ks;
                __builtin_amdgcn_s_setprio(1);
#pragma unroll
                for (int dh = 0; dh < 2; ++dh) {
                    s16x8 vf = *(const s16x8*)(vbase + swzo(dh * 32 + lq, kst * 32 + lh * 16));
                    o[dh] = __builtin_amdgcn_mfma_f32_32x32x16_bf16(fr.v, vf, o[dh], 0, 0, 0);
                }
                __builtin_amdgcn_s_setprio(0);
            }
        }

        // ---- write next V tile ----
#pragma unroll
        for (int dd = 0; dd < 8; ++dd) {
            int d = vd + dd;
            unsigned pkv = (unsigned)(unsigned short)va[dd] | ((unsigned)(unsigned short)vb2[dd] << 16);
            *(unsigned*)((char*)Vt[nxt] + d * 128 + ((vk * 2) ^ ((d & 7) << 4))) = pkv;
        }
        asm volatile("s_waitcnt vmcnt(0) lgkmcnt(0)" ::: "memory");
        __builtin_amdgcn_s_barrier();
    }

    // lane halves hold partials for q = lq over disjoint key-subsets
    lt_ += __shfl_xor(lt_, 32);
    float inv = 1.0f / lt_;

    const int b = bh >> 4, h = bh & 15;
#pragma unroll
    for (int r = 0; r < 16; ++r) {
        int qrow = (r & 3) + 8 * (r >> 2) + 4 * lh;
        float iv = __shfl(inv, qrow | (l & 32));
        int s = q0 + qrow;
        size_t base = ((size_t)b * 2048 + s) * 1024 + h * 64;
#pragma unroll
        for (int dh = 0; dh < 2; ++dh)
            AO[base + dh * 32 + lq] = f2bf(o[dh][r] * iv);
    }
}

// ---------------- Kernel 3: out = AO @ W_out + b_out ----------------
// 128x128 tile, dbuf LDS (64KB), counted vmcnt(8) pipeline.
__global__ __launch_bounds__(256, 2) void out_gemm_kernel(
    const unsigned short* __restrict__ A, const unsigned short* __restrict__ Wot,
    const float* __restrict__ bias, float* __restrict__ out)
{
    __shared__ alignas(16) short As[2][128 * 64];
    __shared__ alignas(16) short Bs[2][128 * 64];
    const int bid = blockIdx.x;
    const int xcd = bid & 7, ii = bid >> 3;
    const int mb = (xcd & 3) * 8 + (ii & 7);
    const int nb = (xcd >> 2) * 4 + (ii >> 3);
    const int t = threadIdx.x, w = t >> 6, l = t & 63;
    const int g = l >> 4, j = l & 15;
    const int wm = w >> 1, wn = w & 1;
    const int m0 = mb * 128, n0 = nb * 128;

    f32x4 acc[4][4];
#pragma unroll
    for (int mi = 0; mi < 4; ++mi)
#pragma unroll
        for (int ni = 0; ni < 4; ++ni) acc[mi][ni] = (f32x4){0.f, 0.f, 0.f, 0.f};

#pragma unroll
    for (int i = 0; i < 4; ++i) {
        int p = (w * 4 + i) * 1024 + l * 16;
        int r = p >> 7, lb = (p & 127) ^ ((r & 7) << 4);
        gload16(&A[(size_t)(m0 + r) * 1024 + (lb >> 1)], (char*)As[0] + (w * 4 + i) * 1024);
        gload16(&Wot[(size_t)(n0 + r) * 1024 + (lb >> 1)], (char*)Bs[0] + (w * 4 + i) * 1024);
    }
    asm volatile("s_waitcnt vmcnt(0)" ::: "memory");
    __builtin_amdgcn_s_barrier();

    for (int kti = 0; kti < 16; ++kti) {
        const int cur = kti & 1, nxt = cur ^ 1;
        const int ktn = ((kti + 1) & 15) * 64;

#pragma unroll
        for (int i = 0; i < 4; ++i) {
            int p = (w * 4 + i) * 1024 + l * 16;
            int r = p >> 7, lb = (p & 127) ^ ((r & 7) << 4);
            gload16(&A[(size_t)(m0 + r) * 1024 + ktn + (lb >> 1)], (char*)As[nxt] + (w * 4 + i) * 1024);
            gload16(&Wot[(size_t)(n0 + r) * 1024 + ktn + (lb >> 1)], (char*)Bs[nxt] + (w * 4 + i) * 1024);
        }
        asm volatile("s_waitcnt vmcnt(8)" ::: "memory");
        __builtin_amdgcn_s_barrier();

#pragma unroll
        for (int kf = 0; kf < 2; ++kf) {
            s16x8 af[4], bv[4];
#pragma unroll
            for (int mi = 0; mi < 4; ++mi)
                af[mi] = *(const s16x8*)((const char*)As[cur] + swzo(wm * 64 + mi * 16 + j, kf * 64 + g * 16));
#pragma unroll
            for (int ni = 0; ni < 4; ++ni)
                bv[ni] = *(const s16x8*)((const char*)Bs[cur] + swzo(wn * 64 + ni * 16 + j, kf * 64 + g * 16));
            __builtin_amdgcn_s_setprio(1);
#pragma unroll
            for (int mi = 0; mi < 4; ++mi)
#pragma unroll
                for (int ni = 0; ni < 4; ++ni)
                    acc[mi][ni] = __builtin_amdgcn_mfma_f32_16x16x32_bf16(af[mi], bv[ni], acc[mi][ni], 0, 0, 0);
            __builtin_amdgcn_s_setprio(0);
        }
        __builtin_amdgcn_s_barrier();
    }

    const int row0 = m0 + wm * 64;
    const int col0 = n0 + wn * 64;
#pragma unroll
    for (int ni = 0; ni < 4; ++ni) {
        const int col = col0 + ni * 16 + j;
        const float bvv = bias[col];
#pragma unroll
        for (int mi = 0; mi < 4; ++mi)
#pragma unroll
            for (int r = 0; r < 4; ++r) {
                int row = row0 + mi * 16 + g * 4 + r;
                out[(size_t)row * 1024 + col] = acc[mi][ni][r] + bvv;
            }
    }
}

extern "C" void kernel_launch(void* const* d_in, const int* in_sizes, int n_in,
                              void* d_out, int out_size, void* d_ws, size_t ws_size,
                              hipStream_t stream) {
    const float* x     = (const float*)d_in[0];
    const float* cosb  = (const float*)d_in[1];
    const float* sinb  = (const float*)d_in[2];
    const float* W_in  = (const float*)d_in[3];
    const float* b_in  = (const float*)d_in[4];
    const float* W_out = (const float*)d_in[5];
    const float* b_out = (const float*)d_in[6];
    float* out = (float*)d_out;

    const size_t HBUF = 2ull * 16 * 2048 * 64;
    if (ws_size < (4 * HBUF + 1024 * 1024) * sizeof(unsigned short)) return;
    unsigned short* Qb = (unsigned short*)d_ws;
    unsigned short* Kb = Qb + HBUF;
    unsigned short* Vb = Kb + HBUF;
    unsigned short* R  = Vb + HBUF;
    unsigned short* Wt_in = R;                         // 3072*1024 bf16, dead after qkv
    unsigned short* AO    = R;                         // aliased, written by attn
    unsigned short* Wot   = R + HBUF;                  // 1024*1024 bf16 (2MB), own slot
    unsigned short* xbuf  = (unsigned short*)d_out;    // 8MB of 16MB out, dead before out_gemm

    hipLaunchKernelGGL(prep_kernel, dim3(3072), dim3(256), 0, stream,
                       x, xbuf, W_in, Wt_in, W_out, Wot);
    hipLaunchKernelGGL(qkv_rope_kernel, dim3(192), dim3(512), 0, stream,
                       xbuf, Wt_in, b_in, cosb, sinb, Qb, Kb, Vb);
    hipLaunchKernelGGL(attn_kernel, dim3(512), dim3(256), 0, stream,
                       Qb, Kb, Vb, AO);
    hipLaunchKernelGGL(out_gemm_kernel, dim3(256), dim3(256), 0, stream,
                       AO, Wot, b_out, out);
}

// Round 18
// 119.000 us; speedup vs baseline: 1.0530x; 1.0530x over previous
//
#include <hip/hip_runtime.h>
#include <hip/hip_bf16.h>

typedef float f32x4 __attribute__((ext_vector_type(4)));
typedef short s16x8 __attribute__((ext_vector_type(8)));

typedef const __attribute__((address_space(1))) unsigned int* as1u;
typedef __attribute__((address_space(3))) unsigned int* as3u;

__device__ __forceinline__ unsigned short f2bf(float f) {
    union { float f; unsigned u; } v; v.f = f;
    unsigned u = v.u;
    u += 0x7fffu + ((u >> 16) & 1u);
    return (unsigned short)(u >> 16);
}

__device__ __forceinline__ void gload16(const void* g, void* l3) {
    __builtin_amdgcn_global_load_lds((as1u)g, (as3u)l3, 16, 0, 0);
}

// XOR-swizzled byte offset for [R][64]-bf16 tiles (128B rows)
__device__ __forceinline__ int swzo(int row, int cb) {
    return row * 128 + (cb ^ ((row & 7) << 4));
}

#define LOG2E 1.4426950408889634f
#define QSCALE (0.125f * LOG2E)   // 1/sqrt(64) * log2(e), folded into Q

// ------------- Kernel P: fused prep -------------
__global__ __launch_bounds__(256) void prep_kernel(
    const float* __restrict__ x, unsigned short* __restrict__ xb,
    const float* __restrict__ W_in, unsigned short* __restrict__ Wt_in,
    const float* __restrict__ W_out, unsigned short* __restrict__ Wot)
{
    const int t = threadIdx.x;
    int blk = blockIdx.x;
    if (blk < 2048) {
        size_t i = ((size_t)blk * 256 + t) * 8;
        float4 a = *(const float4*)&x[i];
        float4 b = *(const float4*)&x[i + 4];
        s16x8 p;
        p[0] = (short)f2bf(a.x); p[1] = (short)f2bf(a.y);
        p[2] = (short)f2bf(a.z); p[3] = (short)f2bf(a.w);
        p[4] = (short)f2bf(b.x); p[5] = (short)f2bf(b.y);
        p[6] = (short)f2bf(b.z); p[7] = (short)f2bf(b.w);
        *(s16x8*)&xb[i] = p;
        return;
    }
    const float* W;
    unsigned short* Wt;
    int N;
    if (blk < 2816) { blk -= 2048; W = W_in;  Wt = Wt_in; N = 3072; }
    else            { blk -= 2816; W = W_out; Wt = Wot;   N = 1024; }
    __shared__ alignas(16) short T[64 * 64];
    const int KB = 16;
    const int kb = blk % KB, nb = blk / KB;
#pragma unroll
    for (int pass = 0; pass < 4; ++pass) {
        int k = pass * 16 + (t >> 4);
        int n4 = (t & 15) * 4;
        float4 v = *(const float4*)&W[(size_t)(kb * 64 + k) * N + nb * 64 + n4];
        short4 s4;
        s4.x = (short)f2bf(v.x); s4.y = (short)f2bf(v.y);
        s4.z = (short)f2bf(v.z); s4.w = (short)f2bf(v.w);
        *(short4*)((char*)T + k * 128 + ((n4 * 2) ^ ((k & 7) << 4))) = s4;
    }
    __syncthreads();
#pragma unroll
    for (int pass = 0; pass < 4; ++pass) {
        int n = pass * 16 + (t >> 4);
        int k4 = (t & 15) * 4;
        short4 s4;
        s4.x = *(const short*)((const char*)T + (k4 + 0) * 128 + ((n * 2) ^ (((k4 + 0) & 7) << 4)));
        s4.y = *(const short*)((const char*)T + (k4 + 1) * 128 + ((n * 2) ^ (((k4 + 1) & 7) << 4)));
        s4.z = *(const short*)((const char*)T + (k4 + 2) * 128 + ((n * 2) ^ (((k4 + 2) & 7) << 4)));
        s4.w = *(const short*)((const char*)T + (k4 + 3) * 128 + ((n * 2) ^ (((k4 + 3) & 7) << 4)));
        *(short4*)&Wt[(size_t)(nb * 64 + n) * 1024 + kb * 64 + k4] = s4;
    }
}

// ---------------- Kernel 1: qkv = x @ W_in + b_in, fused RoPE ----------------
// 256x256 tile, BK=64, 8 waves, LDS 128KB dbuf, counted vmcnt(8) pipeline.
__global__ __launch_bounds__(512, 2) void qkv_rope_kernel(
    const unsigned short* __restrict__ xb, const unsigned short* __restrict__ Wt,
    const float* __restrict__ bias, const float* __restrict__ cosb,
    const float* __restrict__ sinb,
    unsigned short* __restrict__ Qb, unsigned short* __restrict__ Kb,
    unsigned short* __restrict__ Vb)
{
    __shared__ alignas(16) short As[2][256 * 64];
    __shared__ alignas(16) short Bs[2][256 * 64];
    const int bid = blockIdx.x;
    const int mb = bid & 15, nb = bid >> 4;
    const int t = threadIdx.x, w = t >> 6, l = t & 63;
    const int g = l >> 4, j = l & 15;
    const int wm = w >> 2, wn = w & 3;
    const int m0 = mb * 256, n0 = nb * 256;

    f32x4 acc[8][4];
#pragma unroll
    for (int mi = 0; mi < 8; ++mi)
#pragma unroll
        for (int ni = 0; ni < 4; ++ni) acc[mi][ni] = (f32x4){0.f, 0.f, 0.f, 0.f};

#pragma unroll
    for (int i = 0; i < 4; ++i) {
        int p = (w * 4 + i) * 1024 + l * 16;
        int r = p >> 7, lb = (p & 127) ^ ((r & 7) << 4);
        gload16(&xb[(size_t)(m0 + r) * 1024 + (lb >> 1)], (char*)As[0] + (w * 4 + i) * 1024);
        gload16(&Wt[(size_t)(n0 + r) * 1024 + (lb >> 1)], (char*)Bs[0] + (w * 4 + i) * 1024);
    }
    asm volatile("s_waitcnt vmcnt(0)" ::: "memory");
    __builtin_amdgcn_s_barrier();

    for (int kti = 0; kti < 16; ++kti) {
        const int cur = kti & 1, nxt = cur ^ 1;
        const int ktn = ((kti + 1) & 15) * 64;

#pragma unroll
        for (int i = 0; i < 4; ++i) {
            int p = (w * 4 + i) * 1024 + l * 16;
            int r = p >> 7, lb = (p & 127) ^ ((r & 7) << 4);
            gload16(&xb[(size_t)(m0 + r) * 1024 + ktn + (lb >> 1)], (char*)As[nxt] + (w * 4 + i) * 1024);
            gload16(&Wt[(size_t)(n0 + r) * 1024 + ktn + (lb >> 1)], (char*)Bs[nxt] + (w * 4 + i) * 1024);
        }
        asm volatile("s_waitcnt vmcnt(8)" ::: "memory");
        __builtin_amdgcn_s_barrier();

#pragma unroll
        for (int kf = 0; kf < 2; ++kf) {
            s16x8 bv[4];
#pragma unroll
            for (int ni = 0; ni < 4; ++ni)
                bv[ni] = *(const s16x8*)((const char*)Bs[cur] + swzo(wn * 64 + ni * 16 + j, kf * 64 + g * 16));
#pragma unroll
            for (int mh = 0; mh < 2; ++mh) {
                s16x8 af[4];
#pragma unroll
                for (int mi = 0; mi < 4; ++mi)
                    af[mi] = *(const s16x8*)((const char*)As[cur] + swzo(wm * 128 + mh * 64 + mi * 16 + j, kf * 64 + g * 16));
                __builtin_amdgcn_s_setprio(1);
#pragma unroll
                for (int mi = 0; mi < 4; ++mi)
#pragma unroll
                    for (int ni = 0; ni < 4; ++ni)
                        acc[mh * 4 + mi][ni] = __builtin_amdgcn_mfma_f32_16x16x32_bf16(af[mi], bv[ni], acc[mh * 4 + mi][ni], 0, 0, 0);
                __builtin_amdgcn_s_setprio(0);
            }
        }
        __builtin_amdgcn_s_barrier();
    }

    const int row0 = m0 + wm * 128;
    const int col0 = n0 + wn * 64;
    const int sec = col0 >> 10;
    const int h = (col0 & 1023) >> 6;

    if (sec < 2) {
        unsigned short* dst = (sec == 0) ? Qb : Kb;
        const float qs = (sec == 0) ? QSCALE : 1.0f;
#pragma unroll
        for (int nt = 0; nt < 2; ++nt) {
            const int d = nt * 16 + j;
            const float b1 = bias[col0 + d];
            const float b2 = bias[col0 + d + 32];
#pragma unroll
            for (int mi = 0; mi < 8; ++mi) {
#pragma unroll
                for (int r = 0; r < 4; ++r) {
                    int row = row0 + mi * 16 + g * 4 + r;
                    int s = row & 2047, bb = row >> 11;
                    float c = cosb[s * 64 + d], sn = sinb[s * 64 + d];
                    float x1 = acc[mi][nt][r] + b1;
                    float x2 = acc[mi][nt + 2][r] + b2;
                    float lo = (x1 * c - x2 * sn) * qs;
                    float hi = (x1 * sn + x2 * c) * qs;
                    size_t base = ((size_t)(bb * 16 + h) * 2048 + s) * 64;
                    dst[base + d] = f2bf(lo);
                    dst[base + d + 32] = f2bf(hi);
                }
            }
        }
    } else {
#pragma unroll
        for (int nt = 0; nt < 4; ++nt) {
            const int d = nt * 16 + j;
            const float bvv = bias[col0 + d];
#pragma unroll
            for (int mi = 0; mi < 8; ++mi) {
#pragma unroll
                for (int r = 0; r < 4; ++r) {
                    int row = row0 + mi * 16 + g * 4 + r;
                    int s = row & 2047, bb = row >> 11;
                    size_t base = ((size_t)(bb * 16 + h) * 2048 + s) * 64;
                    Vb[base + d] = f2bf(acc[mi][nt][r] + bvv);
                }
            }
        }
    }
}

// ---------------- Kernel 2: flash attention (R11 structure, best known) ----------------
// 8 waves x 16 q-rows = 128 q/block, grid 512, XCD-swizzled heads (K/V L2-resident).
// KVBLK=128 (2 KV-tiles per barrier round). Role-split staging.
// Swapped-QK in-register softmax, fixed max (m=0).
// P->PV redistribution via permlane32+permlane16 swaps.
#define NROUND 16
__global__ __launch_bounds__(512, 4) void attn_kernel(
    const unsigned short* __restrict__ Qb, const unsigned short* __restrict__ Kb,
    const unsigned short* __restrict__ Vb, unsigned short* __restrict__ AO)
{
    __shared__ alignas(16) short Ks[2][2 * 64 * 64];
    __shared__ alignas(16) short Vt[2][2 * 64 * 64];
    const int bid = blockIdx.x;
    const int bh = (bid & 7) + ((bid >> 7) << 3);
    const int qt = (bid >> 3) & 15;
    const int t = threadIdx.x, w = t >> 6, l = t & 63;
    const int g = l >> 4, j = l & 15;
    const unsigned short* Qh = Qb + (size_t)bh * 131072;
    const unsigned short* Kh = Kb + (size_t)bh * 131072;
    const unsigned short* Vh = Vb + (size_t)bh * 131072;
    const int q0 = qt * 128 + w * 16;

    s16x8 aq[2];
    aq[0] = *(const s16x8*)&Qh[(size_t)(q0 + j) * 64 + g * 8];
    aq[1] = *(const s16x8*)&Qh[(size_t)(q0 + j) * 64 + 32 + g * 8];

    float lt_ = 0.f;
    f32x4 o[4];
#pragma unroll
    for (int dt = 0; dt < 4; ++dt) o[dt] = (f32x4){0.f, 0.f, 0.f, 0.f};

    const bool vrole = (w < 4);
    const int tv = t & 255;
    const int vk = (tv & 31) * 2;
    const int vd = (tv >> 5) * 8;
    const int kw = (w & 3);

    s16x8 va[2], vb2[2];

    if (vrole) {
#pragma unroll
        for (int s = 0; s < 2; ++s) {
            va[s]  = *(const s16x8*)&Vh[(size_t)(s * 64 + vk) * 64 + vd];
            vb2[s] = *(const s16x8*)&Vh[(size_t)(s * 64 + vk + 1) * 64 + vd];
        }
    } else {
#pragma unroll
        for (int i = 0; i < 4; ++i) {
            int p = (kw * 4 + i) * 1024 + l * 16;
            int s = p >> 13, q = p & 8191;
            int r = q >> 7, lb = (q & 127) ^ ((r & 7) << 4);
            gload16(&Kh[(size_t)(s * 64 + r) * 64 + (lb >> 1)],
                    (char*)Ks[0] + (kw * 4 + i) * 1024);
        }
    }
    asm volatile("s_waitcnt vmcnt(0)" ::: "memory");
    if (vrole) {
#pragma unroll
        for (int s = 0; s < 2; ++s)
#pragma unroll
            for (int dd = 0; dd < 8; ++dd) {
                int d = vd + dd;
                unsigned pkv = (unsigned)(unsigned short)va[s][dd] | ((unsigned)(unsigned short)vb2[s][dd] << 16);
                *(unsigned*)((char*)Vt[0] + s * 8192 + d * 128 + ((vk * 2) ^ ((d & 7) << 4))) = pkv;
            }
    }
    asm volatile("s_waitcnt lgkmcnt(0)" ::: "memory");
    __builtin_amdgcn_s_barrier();

    for (int rr = 0; rr < NROUND; ++rr) {
        const int cur = rr & 1, nxt = cur ^ 1;
        const int kvp = ((rr + 1) & (NROUND - 1)) * 128;

        if (vrole) {
#pragma unroll
            for (int s = 0; s < 2; ++s) {
                va[s]  = *(const s16x8*)&Vh[(size_t)(kvp + s * 64 + vk) * 64 + vd];
                vb2[s] = *(const s16x8*)&Vh[(size_t)(kvp + s * 64 + vk + 1) * 64 + vd];
            }
        } else {
#pragma unroll
            for (int i = 0; i < 4; ++i) {
                int p = (kw * 4 + i) * 1024 + l * 16;
                int s = p >> 13, q = p & 8191;
                int r = q >> 7, lb = (q & 127) ^ ((r & 7) << 4);
                gload16(&Kh[(size_t)(kvp + s * 64 + r) * 64 + (lb >> 1)],
                        (char*)Ks[nxt] + (kw * 4 + i) * 1024);
            }
        }

        f32x4 sc[2][4];
#pragma unroll
        for (int sub = 0; sub < 2; ++sub)
#pragma unroll
            for (int nt = 0; nt < 4; ++nt) sc[sub][nt] = (f32x4){0.f, 0.f, 0.f, 0.f};
        __builtin_amdgcn_s_setprio(1);
#pragma unroll
        for (int sub = 0; sub < 2; ++sub) {
            const char* kbase = (const char*)Ks[cur] + sub * 8192;
#pragma unroll
            for (int kf = 0; kf < 2; ++kf) {
                s16x8 bk[4];
#pragma unroll
                for (int nt = 0; nt < 4; ++nt)
                    bk[nt] = *(const s16x8*)(kbase + swzo(nt * 16 + j, kf * 64 + g * 16));
#pragma unroll
                for (int nt = 0; nt < 4; ++nt)
                    sc[sub][nt] = __builtin_amdgcn_mfma_f32_16x16x32_bf16(bk[nt], aq[kf], sc[sub][nt], 0, 0, 0);
            }
        }
        __builtin_amdgcn_s_setprio(0);

#pragma unroll
        for (int sub = 0; sub < 2; ++sub) {
            const char* vbase = (const char*)Vt[cur] + sub * 8192;

            float rs = 0.f;
#pragma unroll
            for (int nt = 0; nt < 4; ++nt)
#pragma unroll
                for (int r = 0; r < 4; ++r) {
                    sc[sub][nt][r] = __builtin_amdgcn_exp2f(sc[sub][nt][r]);
                    rs += sc[sub][nt][r];
                }
            lt_ += rs;

            unsigned pk[4][2];
#pragma unroll
            for (int nt = 0; nt < 4; ++nt)
#pragma unroll
                for (int s = 0; s < 2; ++s)
                    asm("v_cvt_pk_bf16_f32 %0, %1, %2"
                        : "=v"(pk[nt][s]) : "v"(sc[sub][nt][2 * s]), "v"(sc[sub][nt][2 * s + 1]));

#pragma unroll
            for (int kf = 0; kf < 2; ++kf) {
                unsigned A0 = pk[2 * kf][0], A1 = pk[2 * kf][1];
                unsigned B0 = pk[2 * kf + 1][0], B1 = pk[2 * kf + 1][1];
                asm("v_permlane32_swap_b32 %0, %1" : "+v"(A0), "+v"(B0));
                asm("v_permlane32_swap_b32 %0, %1" : "+v"(A1), "+v"(B1));
                asm("v_permlane16_swap_b32 %0, %1" : "+v"(A0), "+v"(B0));
                asm("v_permlane16_swap_b32 %0, %1" : "+v"(A1), "+v"(B1));
                union { unsigned u[4]; s16x8 v; } fr;
                fr.u[0] = A0;
                fr.u[1] = A1;
                fr.u[2] = B0;
                fr.u[3] = B1;
                __builtin_amdgcn_s_setprio(1);
#pragma unroll
                for (int dt = 0; dt < 4; ++dt) {
                    s16x8 vb = *(const s16x8*)(vbase + swzo(dt * 16 + j, kf * 64 + g * 16));
                    o[dt] = __builtin_amdgcn_mfma_f32_16x16x32_bf16(fr.v, vb, o[dt], 0, 0, 0);
                }
                __builtin_amdgcn_s_setprio(0);
            }
        }

        if (vrole) {
#pragma unroll
            for (int s = 0; s < 2; ++s)
#pragma unroll
                for (int dd = 0; dd < 8; ++dd) {
                    int d = vd + dd;
                    unsigned pkv = (unsigned)(unsigned short)va[s][dd] | ((unsigned)(unsigned short)vb2[s][dd] << 16);
                    *(unsigned*)((char*)Vt[nxt] + s * 8192 + d * 128 + ((vk * 2) ^ ((d & 7) << 4))) = pkv;
                }
        }
        asm volatile("s_waitcnt vmcnt(0) lgkmcnt(0)" ::: "memory");
        __builtin_amdgcn_s_barrier();
    }

    lt_ += __shfl_xor(lt_, 16);
    lt_ += __shfl_xor(lt_, 32);

    const int b = bh >> 4, h = bh & 15;
#pragma unroll
    for (int r = 0; r < 4; ++r) {
        float inv = 1.0f / __shfl(lt_, g * 4 + r);
        int s = q0 + g * 4 + r;
        size_t base = ((size_t)b * 2048 + s) * 1024 + h * 64;
#pragma unroll
        for (int dt = 0; dt < 4; ++dt)
            AO[base + dt * 16 + j] = f2bf(o[dt][r] * inv);
    }
}

// ---------------- Kernel 3: out = AO @ W_out + b_out ----------------
// 128x128 tile, dbuf LDS (64KB), counted vmcnt(8) pipeline.
__global__ __launch_bounds__(256, 2) void out_gemm_kernel(
    const unsigned short* __restrict__ A, const unsigned short* __restrict__ Wot,
    const float* __restrict__ bias, float* __restrict__ out)
{
    __shared__ alignas(16) short As[2][128 * 64];
    __shared__ alignas(16) short Bs[2][128 * 64];
    const int bid = blockIdx.x;
    const int xcd = bid & 7, ii = bid >> 3;
    const int mb = (xcd & 3) * 8 + (ii & 7);
    const int nb = (xcd >> 2) * 4 + (ii >> 3);
    const int t = threadIdx.x, w = t >> 6, l = t & 63;
    const int g = l >> 4, j = l & 15;
    const int wm = w >> 1, wn = w & 1;
    const int m0 = mb * 128, n0 = nb * 128;

    f32x4 acc[4][4];
#pragma unroll
    for (int mi = 0; mi < 4; ++mi)
#pragma unroll
        for (int ni = 0; ni < 4; ++ni) acc[mi][ni] = (f32x4){0.f, 0.f, 0.f, 0.f};

#pragma unroll
    for (int i = 0; i < 4; ++i) {
        int p = (w * 4 + i) * 1024 + l * 16;
        int r = p >> 7, lb = (p & 127) ^ ((r & 7) << 4);
        gload16(&A[(size_t)(m0 + r) * 1024 + (lb >> 1)], (char*)As[0] + (w * 4 + i) * 1024);
        gload16(&Wot[(size_t)(n0 + r) * 1024 + (lb >> 1)], (char*)Bs[0] + (w * 4 + i) * 1024);
    }
    asm volatile("s_waitcnt vmcnt(0)" ::: "memory");
    __builtin_amdgcn_s_barrier();

    for (int kti = 0; kti < 16; ++kti) {
        const int cur = kti & 1, nxt = cur ^ 1;
        const int ktn = ((kti + 1) & 15) * 64;

#pragma unroll
        for (int i = 0; i < 4; ++i) {
            int p = (w * 4 + i) * 1024 + l * 16;
            int r = p >> 7, lb = (p & 127) ^ ((r & 7) << 4);
            gload16(&A[(size_t)(m0 + r) * 1024 + ktn + (lb >> 1)], (char*)As[nxt] + (w * 4 + i) * 1024);
            gload16(&Wot[(size_t)(n0 + r) * 1024 + ktn + (lb >> 1)], (char*)Bs[nxt] + (w * 4 + i) * 1024);
        }
        asm volatile("s_waitcnt vmcnt(8)" ::: "memory");
        __builtin_amdgcn_s_barrier();

#pragma unroll
        for (int kf = 0; kf < 2; ++kf) {
            s16x8 af[4], bv[4];
#pragma unroll
            for (int mi = 0; mi < 4; ++mi)
                af[mi] = *(const s16x8*)((const char*)As[cur] + swzo(wm * 64 + mi * 16 + j, kf * 64 + g * 16));
#pragma unroll
            for (int ni = 0; ni < 4; ++ni)
                bv[ni] = *(const s16x8*)((const char*)Bs[cur] + swzo(wn * 64 + ni * 16 + j, kf * 64 + g * 16));
            __builtin_amdgcn_s_setprio(1);
#pragma unroll
            for (int mi = 0; mi < 4; ++mi)
#pragma unroll
                for (int ni = 0; ni < 4; ++ni)
                    acc[mi][ni] = __builtin_amdgcn_mfma_f32_16x16x32_bf16(af[mi], bv[ni], acc[mi][ni], 0, 0, 0);
            __builtin_amdgcn_s_setprio(0);
        }
        __builtin_amdgcn_s_barrier();
    }

    const int row0 = m0 + wm * 64;
    const int col0 = n0 + wn * 64;
#pragma unroll
    for (int ni = 0; ni < 4; ++ni) {
        const int col = col0 + ni * 16 + j;
        const float bvv = bias[col];
#pragma unroll
        for (int mi = 0; mi < 4; ++mi)
#pragma unroll
            for (int r = 0; r < 4; ++r) {
                int row = row0 + mi * 16 + g * 4 + r;
                out[(size_t)row * 1024 + col] = acc[mi][ni][r] + bvv;
            }
    }
}

extern "C" void kernel_launch(void* const* d_in, const int* in_sizes, int n_in,
                              void* d_out, int out_size, void* d_ws, size_t ws_size,
                              hipStream_t stream) {
    const float* x     = (const float*)d_in[0];
    const float* cosb  = (const float*)d_in[1];
    const float* sinb  = (const float*)d_in[2];
    const float* W_in  = (const float*)d_in[3];
    const float* b_in  = (const float*)d_in[4];
    const float* W_out = (const float*)d_in[5];
    const float* b_out = (const float*)d_in[6];
    float* out = (float*)d_out;

    const size_t HBUF = 2ull * 16 * 2048 * 64;
    if (ws_size < (4 * HBUF + 1024 * 1024) * sizeof(unsigned short)) return;
    unsigned short* Qb = (unsigned short*)d_ws;
    unsigned short* Kb = Qb + HBUF;
    unsigned short* Vb = Kb + HBUF;
    unsigned short* R  = Vb + HBUF;
    unsigned short* Wt_in = R;                         // 3072*1024 bf16, dead after qkv
    unsigned short* AO    = R;                         // aliased, written by attn
    unsigned short* Wot   = R + HBUF;                  // 1024*1024 bf16 (2MB), own slot
    unsigned short* xbuf  = (unsigned short*)d_out;    // 8MB of 16MB out, dead before out_gemm

    hipLaunchKernelGGL(prep_kernel, dim3(3072), dim3(256), 0, stream,
                       x, xbuf, W_in, Wt_in, W_out, Wot);
    hipLaunchKernelGGL(qkv_rope_kernel, dim3(192), dim3(512), 0, stream,
                       xbuf, Wt_in, b_in, cosb, sinb, Qb, Kb, Vb);
    hipLaunchKernelGGL(attn_kernel, dim3(512), dim3(512), 0, stream,
                       Qb, Kb, Vb, AO);
    hipLaunchKernelGGL(out_gemm_kernel, dim3(256), dim3(256), 0, stream,
                       AO, Wot, b_out, out);
}

// Round 19
// 112.473 us; speedup vs baseline: 1.1141x; 1.0580x over previous
//
#include <hip/hip_runtime.h>
#include <hip/hip_bf16.h>

typedef float f32x4 __attribute__((ext_vector_type(4)));
typedef short s16x8 __attribute__((ext_vector_type(8)));

typedef const __attribute__((address_space(1))) unsigned int* as1u;
typedef __attribute__((address_space(3))) unsigned int* as3u;

__device__ __forceinline__ unsigned short f2bf(float f) {
    union { float f; unsigned u; } v; v.f = f;
    unsigned u = v.u;
    u += 0x7fffu + ((u >> 16) & 1u);
    return (unsigned short)(u >> 16);
}

__device__ __forceinline__ void gload16(const void* g, void* l3) {
    __builtin_amdgcn_global_load_lds((as1u)g, (as3u)l3, 16, 0, 0);
}

// XOR-swizzled byte offset for [R][64]-bf16 tiles (128B rows)
__device__ __forceinline__ int swzo(int row, int cb) {
    return row * 128 + (cb ^ ((row & 7) << 4));
}

#define LOG2E 1.4426950408889634f
#define QSCALE (0.125f * LOG2E)   // 1/sqrt(64) * log2(e), folded into Q

// ------------- Kernel P: fused prep -------------
__global__ __launch_bounds__(256) void prep_kernel(
    const float* __restrict__ x, unsigned short* __restrict__ xb,
    const float* __restrict__ W_in, unsigned short* __restrict__ Wt_in,
    const float* __restrict__ W_out, unsigned short* __restrict__ Wot)
{
    const int t = threadIdx.x;
    int blk = blockIdx.x;
    if (blk < 2048) {
        size_t i = ((size_t)blk * 256 + t) * 8;
        float4 a = *(const float4*)&x[i];
        float4 b = *(const float4*)&x[i + 4];
        s16x8 p;
        p[0] = (short)f2bf(a.x); p[1] = (short)f2bf(a.y);
        p[2] = (short)f2bf(a.z); p[3] = (short)f2bf(a.w);
        p[4] = (short)f2bf(b.x); p[5] = (short)f2bf(b.y);
        p[6] = (short)f2bf(b.z); p[7] = (short)f2bf(b.w);
        *(s16x8*)&xb[i] = p;
        return;
    }
    const float* W;
    unsigned short* Wt;
    int N;
    if (blk < 2816) { blk -= 2048; W = W_in;  Wt = Wt_in; N = 3072; }
    else            { blk -= 2816; W = W_out; Wt = Wot;   N = 1024; }
    __shared__ alignas(16) short T[64 * 64];
    const int KB = 16;
    const int kb = blk % KB, nb = blk / KB;
#pragma unroll
    for (int pass = 0; pass < 4; ++pass) {
        int k = pass * 16 + (t >> 4);
        int n4 = (t & 15) * 4;
        float4 v = *(const float4*)&W[(size_t)(kb * 64 + k) * N + nb * 64 + n4];
        short4 s4;
        s4.x = (short)f2bf(v.x); s4.y = (short)f2bf(v.y);
        s4.z = (short)f2bf(v.z); s4.w = (short)f2bf(v.w);
        *(short4*)((char*)T + k * 128 + ((n4 * 2) ^ ((k & 7) << 4))) = s4;
    }
    __syncthreads();
#pragma unroll
    for (int pass = 0; pass < 4; ++pass) {
        int n = pass * 16 + (t >> 4);
        int k4 = (t & 15) * 4;
        short4 s4;
        s4.x = *(const short*)((const char*)T + (k4 + 0) * 128 + ((n * 2) ^ (((k4 + 0) & 7) << 4)));
        s4.y = *(const short*)((const char*)T + (k4 + 1) * 128 + ((n * 2) ^ (((k4 + 1) & 7) << 4)));
        s4.z = *(const short*)((const char*)T + (k4 + 2) * 128 + ((n * 2) ^ (((k4 + 2) & 7) << 4)));
        s4.w = *(const short*)((const char*)T + (k4 + 3) * 128 + ((n * 2) ^ (((k4 + 3) & 7) << 4)));
        *(short4*)&Wt[(size_t)(nb * 64 + n) * 1024 + kb * 64 + k4] = s4;
    }
}

// ---------------- Kernel 1: qkv = x @ W_in + b_in, fused RoPE ----------------
// 256x256 tile, BK=64, 16 waves x 64x64 output, LDS 128KB dbuf,
// counted vmcnt(4) pipeline. 16 waves/CU (4/SIMD).
__global__ __launch_bounds__(1024, 1) void qkv_rope_kernel(
    const unsigned short* __restrict__ xb, const unsigned short* __restrict__ Wt,
    const float* __restrict__ bias, const float* __restrict__ cosb,
    const float* __restrict__ sinb,
    unsigned short* __restrict__ Qb, unsigned short* __restrict__ Kb,
    unsigned short* __restrict__ Vb)
{
    __shared__ alignas(16) short As[2][256 * 64];
    __shared__ alignas(16) short Bs[2][256 * 64];
    const int bid = blockIdx.x;
    const int mb = bid & 15, nb = bid >> 4;
    const int t = threadIdx.x, w = t >> 6, l = t & 63;
    const int g = l >> 4, j = l & 15;
    const int wm = w >> 2, wn = w & 3;          // 4M x 4N waves, 64x64 each
    const int m0 = mb * 256, n0 = nb * 256;

    f32x4 acc[4][4];
#pragma unroll
    for (int mi = 0; mi < 4; ++mi)
#pragma unroll
        for (int ni = 0; ni < 4; ++ni) acc[mi][ni] = (f32x4){0.f, 0.f, 0.f, 0.f};

#pragma unroll
    for (int i = 0; i < 2; ++i) {
        int p = (w * 2 + i) * 1024 + l * 16;
        int r = p >> 7, lb = (p & 127) ^ ((r & 7) << 4);
        gload16(&xb[(size_t)(m0 + r) * 1024 + (lb >> 1)], (char*)As[0] + (w * 2 + i) * 1024);
        gload16(&Wt[(size_t)(n0 + r) * 1024 + (lb >> 1)], (char*)Bs[0] + (w * 2 + i) * 1024);
    }
    asm volatile("s_waitcnt vmcnt(0)" ::: "memory");
    __builtin_amdgcn_s_barrier();

    for (int kti = 0; kti < 16; ++kti) {
        const int cur = kti & 1, nxt = cur ^ 1;
        const int ktn = ((kti + 1) & 15) * 64;

#pragma unroll
        for (int i = 0; i < 2; ++i) {
            int p = (w * 2 + i) * 1024 + l * 16;
            int r = p >> 7, lb = (p & 127) ^ ((r & 7) << 4);
            gload16(&xb[(size_t)(m0 + r) * 1024 + ktn + (lb >> 1)], (char*)As[nxt] + (w * 2 + i) * 1024);
            gload16(&Wt[(size_t)(n0 + r) * 1024 + ktn + (lb >> 1)], (char*)Bs[nxt] + (w * 2 + i) * 1024);
        }
        asm volatile("s_waitcnt vmcnt(4)" ::: "memory");
        __builtin_amdgcn_s_barrier();

#pragma unroll
        for (int kf = 0; kf < 2; ++kf) {
            s16x8 bv[4], af[4];
#pragma unroll
            for (int ni = 0; ni < 4; ++ni)
                bv[ni] = *(const s16x8*)((const char*)Bs[cur] + swzo(wn * 64 + ni * 16 + j, kf * 64 + g * 16));
#pragma unroll
            for (int mi = 0; mi < 4; ++mi)
                af[mi] = *(const s16x8*)((const char*)As[cur] + swzo(wm * 64 + mi * 16 + j, kf * 64 + g * 16));
            __builtin_amdgcn_s_setprio(1);
#pragma unroll
            for (int mi = 0; mi < 4; ++mi)
#pragma unroll
                for (int ni = 0; ni < 4; ++ni)
                    acc[mi][ni] = __builtin_amdgcn_mfma_f32_16x16x32_bf16(af[mi], bv[ni], acc[mi][ni], 0, 0, 0);
            __builtin_amdgcn_s_setprio(0);
        }
        __builtin_amdgcn_s_barrier();
    }

    const int row0 = m0 + wm * 64;
    const int col0 = n0 + wn * 64;
    const int sec = col0 >> 10;
    const int h = (col0 & 1023) >> 6;

    if (sec < 2) {
        unsigned short* dst = (sec == 0) ? Qb : Kb;
        const float qs = (sec == 0) ? QSCALE : 1.0f;
#pragma unroll
        for (int nt = 0; nt < 2; ++nt) {
            const int d = nt * 16 + j;
            const float b1 = bias[col0 + d];
            const float b2 = bias[col0 + d + 32];
#pragma unroll
            for (int mi = 0; mi < 4; ++mi) {
#pragma unroll
                for (int r = 0; r < 4; ++r) {
                    int row = row0 + mi * 16 + g * 4 + r;
                    int s = row & 2047, bb = row >> 11;
                    float c = cosb[s * 64 + d], sn = sinb[s * 64 + d];
                    float x1 = acc[mi][nt][r] + b1;
                    float x2 = acc[mi][nt + 2][r] + b2;
                    float lo = (x1 * c - x2 * sn) * qs;
                    float hi = (x1 * sn + x2 * c) * qs;
                    size_t base = ((size_t)(bb * 16 + h) * 2048 + s) * 64;
                    dst[base + d] = f2bf(lo);
                    dst[base + d + 32] = f2bf(hi);
                }
            }
        }
    } else {
#pragma unroll
        for (int nt = 0; nt < 4; ++nt) {
            const int d = nt * 16 + j;
            const float bvv = bias[col0 + d];
#pragma unroll
            for (int mi = 0; mi < 4; ++mi) {
#pragma unroll
                for (int r = 0; r < 4; ++r) {
                    int row = row0 + mi * 16 + g * 4 + r;
                    int s = row & 2047, bb = row >> 11;
                    size_t base = ((size_t)(bb * 16 + h) * 2048 + s) * 64;
                    Vb[base + d] = f2bf(acc[mi][nt][r] + bvv);
                }
            }
        }
    }
}

// ---------------- Kernel 2: flash attention (R11 structure, best known) ----------------
#define NROUND 16
__global__ __launch_bounds__(512, 4) void attn_kernel(
    const unsigned short* __restrict__ Qb, const unsigned short* __restrict__ Kb,
    const unsigned short* __restrict__ Vb, unsigned short* __restrict__ AO)
{
    __shared__ alignas(16) short Ks[2][2 * 64 * 64];
    __shared__ alignas(16) short Vt[2][2 * 64 * 64];
    const int bid = blockIdx.x;
    const int bh = (bid & 7) + ((bid >> 7) << 3);
    const int qt = (bid >> 3) & 15;
    const int t = threadIdx.x, w = t >> 6, l = t & 63;
    const int g = l >> 4, j = l & 15;
    const unsigned short* Qh = Qb + (size_t)bh * 131072;
    const unsigned short* Kh = Kb + (size_t)bh * 131072;
    const unsigned short* Vh = Vb + (size_t)bh * 131072;
    const int q0 = qt * 128 + w * 16;

    s16x8 aq[2];
    aq[0] = *(const s16x8*)&Qh[(size_t)(q0 + j) * 64 + g * 8];
    aq[1] = *(const s16x8*)&Qh[(size_t)(q0 + j) * 64 + 32 + g * 8];

    float lt_ = 0.f;
    f32x4 o[4];
#pragma unroll
    for (int dt = 0; dt < 4; ++dt) o[dt] = (f32x4){0.f, 0.f, 0.f, 0.f};

    const bool vrole = (w < 4);
    const int tv = t & 255;
    const int vk = (tv & 31) * 2;
    const int vd = (tv >> 5) * 8;
    const int kw = (w & 3);

    s16x8 va[2], vb2[2];

    if (vrole) {
#pragma unroll
        for (int s = 0; s < 2; ++s) {
            va[s]  = *(const s16x8*)&Vh[(size_t)(s * 64 + vk) * 64 + vd];
            vb2[s] = *(const s16x8*)&Vh[(size_t)(s * 64 + vk + 1) * 64 + vd];
        }
    } else {
#pragma unroll
        for (int i = 0; i < 4; ++i) {
            int p = (kw * 4 + i) * 1024 + l * 16;
            int s = p >> 13, q = p & 8191;
            int r = q >> 7, lb = (q & 127) ^ ((r & 7) << 4);
            gload16(&Kh[(size_t)(s * 64 + r) * 64 + (lb >> 1)],
                    (char*)Ks[0] + (kw * 4 + i) * 1024);
        }
    }
    asm volatile("s_waitcnt vmcnt(0)" ::: "memory");
    if (vrole) {
#pragma unroll
        for (int s = 0; s < 2; ++s)
#pragma unroll
            for (int dd = 0; dd < 8; ++dd) {
                int d = vd + dd;
                unsigned pkv = (unsigned)(unsigned short)va[s][dd] | ((unsigned)(unsigned short)vb2[s][dd] << 16);
                *(unsigned*)((char*)Vt[0] + s * 8192 + d * 128 + ((vk * 2) ^ ((d & 7) << 4))) = pkv;
            }
    }
    asm volatile("s_waitcnt lgkmcnt(0)" ::: "memory");
    __builtin_amdgcn_s_barrier();

    for (int rr = 0; rr < NROUND; ++rr) {
        const int cur = rr & 1, nxt = cur ^ 1;
        const int kvp = ((rr + 1) & (NROUND - 1)) * 128;

        if (vrole) {
#pragma unroll
            for (int s = 0; s < 2; ++s) {
                va[s]  = *(const s16x8*)&Vh[(size_t)(kvp + s * 64 + vk) * 64 + vd];
                vb2[s] = *(const s16x8*)&Vh[(size_t)(kvp + s * 64 + vk + 1) * 64 + vd];
            }
        } else {
#pragma unroll
            for (int i = 0; i < 4; ++i) {
                int p = (kw * 4 + i) * 1024 + l * 16;
                int s = p >> 13, q = p & 8191;
                int r = q >> 7, lb = (q & 127) ^ ((r & 7) << 4);
                gload16(&Kh[(size_t)(kvp + s * 64 + r) * 64 + (lb >> 1)],
                        (char*)Ks[nxt] + (kw * 4 + i) * 1024);
            }
        }

        f32x4 sc[2][4];
#pragma unroll
        for (int sub = 0; sub < 2; ++sub)
#pragma unroll
            for (int nt = 0; nt < 4; ++nt) sc[sub][nt] = (f32x4){0.f, 0.f, 0.f, 0.f};
        __builtin_amdgcn_s_setprio(1);
#pragma unroll
        for (int sub = 0; sub < 2; ++sub) {
            const char* kbase = (const char*)Ks[cur] + sub * 8192;
#pragma unroll
            for (int kf = 0; kf < 2; ++kf) {
                s16x8 bk[4];
#pragma unroll
                for (int nt = 0; nt < 4; ++nt)
                    bk[nt] = *(const s16x8*)(kbase + swzo(nt * 16 + j, kf * 64 + g * 16));
#pragma unroll
                for (int nt = 0; nt < 4; ++nt)
                    sc[sub][nt] = __builtin_amdgcn_mfma_f32_16x16x32_bf16(bk[nt], aq[kf], sc[sub][nt], 0, 0, 0);
            }
        }
        __builtin_amdgcn_s_setprio(0);

#pragma unroll
        for (int sub = 0; sub < 2; ++sub) {
            const char* vbase = (const char*)Vt[cur] + sub * 8192;

            float rs = 0.f;
#pragma unroll
            for (int nt = 0; nt < 4; ++nt)
#pragma unroll
                for (int r = 0; r < 4; ++r) {
                    sc[sub][nt][r] = __builtin_amdgcn_exp2f(sc[sub][nt][r]);
                    rs += sc[sub][nt][r];
                }
            lt_ += rs;

            unsigned pk[4][2];
#pragma unroll
            for (int nt = 0; nt < 4; ++nt)
#pragma unroll
                for (int s = 0; s < 2; ++s)
                    asm("v_cvt_pk_bf16_f32 %0, %1, %2"
                        : "=v"(pk[nt][s]) : "v"(sc[sub][nt][2 * s]), "v"(sc[sub][nt][2 * s + 1]));

#pragma unroll
            for (int kf = 0; kf < 2; ++kf) {
                unsigned A0 = pk[2 * kf][0], A1 = pk[2 * kf][1];
                unsigned B0 = pk[2 * kf + 1][0], B1 = pk[2 * kf + 1][1];
                asm("v_permlane32_swap_b32 %0, %1" : "+v"(A0), "+v"(B0));
                asm("v_permlane32_swap_b32 %0, %1" : "+v"(A1), "+v"(B1));
                asm("v_permlane16_swap_b32 %0, %1" : "+v"(A0), "+v"(B0));
                asm("v_permlane16_swap_b32 %0, %1" : "+v"(A1), "+v"(B1));
                union { unsigned u[4]; s16x8 v; } fr;
                fr.u[0] = A0;
                fr.u[1] = A1;
                fr.u[2] = B0;
                fr.u[3] = B1;
                __builtin_amdgcn_s_setprio(1);
#pragma unroll
                for (int dt = 0; dt < 4; ++dt) {
                    s16x8 vb = *(const s16x8*)(vbase + swzo(dt * 16 + j, kf * 64 + g * 16));
                    o[dt] = __builtin_amdgcn_mfma_f32_16x16x32_bf16(fr.v, vb, o[dt], 0, 0, 0);
                }
                __builtin_amdgcn_s_setprio(0);
            }
        }

        if (vrole) {
#pragma unroll
            for (int s = 0; s < 2; ++s)
#pragma unroll
                for (int dd = 0; dd < 8; ++dd) {
                    int d = vd + dd;
                    unsigned pkv = (unsigned)(unsigned short)va[s][dd] | ((unsigned)(unsigned short)vb2[s][dd] << 16);
                    *(unsigned*)((char*)Vt[nxt] + s * 8192 + d * 128 + ((vk * 2) ^ ((d & 7) << 4))) = pkv;
                }
        }
        asm volatile("s_waitcnt vmcnt(0) lgkmcnt(0)" ::: "memory");
        __builtin_amdgcn_s_barrier();
    }

    lt_ += __shfl_xor(lt_, 16);
    lt_ += __shfl_xor(lt_, 32);

    const int b = bh >> 4, h = bh & 15;
#pragma unroll
    for (int r = 0; r < 4; ++r) {
        float inv = 1.0f / __shfl(lt_, g * 4 + r);
        int s = q0 + g * 4 + r;
        size_t base = ((size_t)b * 2048 + s) * 1024 + h * 64;
#pragma unroll
        for (int dt = 0; dt < 4; ++dt)
            AO[base + dt * 16 + j] = f2bf(o[dt][r] * inv);
    }
}

// ---------------- Kernel 3: out = AO @ W_out + b_out ----------------
// 128x128 tile, 8 waves x 64x32 output, dbuf LDS (64KB), counted vmcnt(4).
__global__ __launch_bounds__(512, 2) void out_gemm_kernel(
    const unsigned short* __restrict__ A, const unsigned short* __restrict__ Wot,
    const float* __restrict__ bias, float* __restrict__ out)
{
    __shared__ alignas(16) short As[2][128 * 64];
    __shared__ alignas(16) short Bs[2][128 * 64];
    const int bid = blockIdx.x;
    const int xcd = bid & 7, ii = bid >> 3;
    const int mb = (xcd & 3) * 8 + (ii & 7);
    const int nb = (xcd >> 2) * 4 + (ii >> 3);
    const int t = threadIdx.x, w = t >> 6, l = t & 63;
    const int g = l >> 4, j = l & 15;
    const int wm = w >> 2, wn = w & 3;          // 2M x 4N waves, 64x32 each
    const int m0 = mb * 128, n0 = nb * 128;

    f32x4 acc[4][2];
#pragma unroll
    for (int mi = 0; mi < 4; ++mi)
#pragma unroll
        for (int ni = 0; ni < 2; ++ni) acc[mi][ni] = (f32x4){0.f, 0.f, 0.f, 0.f};

#pragma unroll
    for (int i = 0; i < 2; ++i) {
        int p = (w * 2 + i) * 1024 + l * 16;
        int r = p >> 7, lb = (p & 127) ^ ((r & 7) << 4);
        gload16(&A[(size_t)(m0 + r) * 1024 + (lb >> 1)], (char*)As[0] + (w * 2 + i) * 1024);
        gload16(&Wot[(size_t)(n0 + r) * 1024 + (lb >> 1)], (char*)Bs[0] + (w * 2 + i) * 1024);
    }
    asm volatile("s_waitcnt vmcnt(0)" ::: "memory");
    __builtin_amdgcn_s_barrier();

    for (int kti = 0; kti < 16; ++kti) {
        const int cur = kti & 1, nxt = cur ^ 1;
        const int ktn = ((kti + 1) & 15) * 64;

#pragma unroll
        for (int i = 0; i < 2; ++i) {
            int p = (w * 2 + i) * 1024 + l * 16;
            int r = p >> 7, lb = (p & 127) ^ ((r & 7) << 4);
            gload16(&A[(size_t)(m0 + r) * 1024 + ktn + (lb >> 1)], (char*)As[nxt] + (w * 2 + i) * 1024);
            gload16(&Wot[(size_t)(n0 + r) * 1024 + ktn + (lb >> 1)], (char*)Bs[nxt] + (w * 2 + i) * 1024);
        }
        asm volatile("s_waitcnt vmcnt(4)" ::: "memory");
        __builtin_amdgcn_s_barrier();

#pragma unroll
        for (int kf = 0; kf < 2; ++kf) {
            s16x8 af[4], bv[2];
#pragma unroll
            for (int mi = 0; mi < 4; ++mi)
                af[mi] = *(const s16x8*)((const char*)As[cur] + swzo(wm * 64 + mi * 16 + j, kf * 64 + g * 16));
#pragma unroll
            for (int ni = 0; ni < 2; ++ni)
                bv[ni] = *(const s16x8*)((const char*)Bs[cur] + swzo(wn * 32 + ni * 16 + j, kf * 64 + g * 16));
            __builtin_amdgcn_s_setprio(1);
#pragma unroll
            for (int mi = 0; mi < 4; ++mi)
#pragma unroll
                for (int ni = 0; ni < 2; ++ni)
                    acc[mi][ni] = __builtin_amdgcn_mfma_f32_16x16x32_bf16(af[mi], bv[ni], acc[mi][ni], 0, 0, 0);
            __builtin_amdgcn_s_setprio(0);
        }
        __builtin_amdgcn_s_barrier();
    }

    const int row0 = m0 + wm * 64;
    const int col0 = n0 + wn * 32;
#pragma unroll
    for (int ni = 0; ni < 2; ++ni) {
        const int col = col0 + ni * 16 + j;
        const float bvv = bias[col];
#pragma unroll
        for (int mi = 0; mi < 4; ++mi)
#pragma unroll
            for (int r = 0; r < 4; ++r) {
                int row = row0 + mi * 16 + g * 4 + r;
                out[(size_t)row * 1024 + col] = acc[mi][ni][r] + bvv;
            }
    }
}

extern "C" void kernel_launch(void* const* d_in, const int* in_sizes, int n_in,
                              void* d_out, int out_size, void* d_ws, size_t ws_size,
                              hipStream_t stream) {
    const float* x     = (const float*)d_in[0];
    const float* cosb  = (const float*)d_in[1];
    const float* sinb  = (const float*)d_in[2];
    const float* W_in  = (const float*)d_in[3];
    const float* b_in  = (const float*)d_in[4];
    const float* W_out = (const float*)d_in[5];
    const float* b_out = (const float*)d_in[6];
    float* out = (float*)d_out;

    const size_t HBUF = 2ull * 16 * 2048 * 64;
    if (ws_size < (4 * HBUF + 1024 * 1024) * sizeof(unsigned short)) return;
    unsigned short* Qb = (unsigned short*)d_ws;
    unsigned short* Kb = Qb + HBUF;
    unsigned short* Vb = Kb + HBUF;
    unsigned short* R  = Vb + HBUF;
    unsigned short* Wt_in = R;                         // 3072*1024 bf16, dead after qkv
    unsigned short* AO    = R;                         // aliased, written by attn
    unsigned short* Wot   = R + HBUF;                  // 1024*1024 bf16 (2MB), own slot
    unsigned short* xbuf  = (unsigned short*)d_out;    // 8MB of 16MB out, dead before out_gemm

    hipLaunchKernelGGL(prep_kernel, dim3(3072), dim3(256), 0, stream,
                       x, xbuf, W_in, Wt_in, W_out, Wot);
    hipLaunchKernelGGL(qkv_rope_kernel, dim3(192), dim3(1024), 0, stream,
                       xbuf, Wt_in, b_in, cosb, sinb, Qb, Kb, Vb);
    hipLaunchKernelGGL(attn_kernel, dim3(512), dim3(512), 0, stream,
                       Qb, Kb, Vb, AO);
    hipLaunchKernelGGL(out_gemm_kernel, dim3(256), dim3(512), 0, stream,
                       AO, Wot, b_out, out);
}